// Round 6
// baseline (560.820 us; speedup 1.0000x reference)
//
#include <hip/hip_runtime.h>

typedef unsigned short u16;
typedef __attribute__((ext_vector_type(4))) u16 u16x4;
typedef __attribute__((ext_vector_type(8))) u16 u16x8;
typedef __attribute__((ext_vector_type(8))) short bf16x8;
typedef __attribute__((ext_vector_type(4))) float f32x4;

// Problem constants
#define BB 2
#define TT 2048
#define DD 768
#define NH 12
#define HDIM 64
#define NQKV 2304   // 3*DD
#define MM 4096     // BB*TT

__device__ __forceinline__ u16 f2bf(float f) {
  unsigned u = __float_as_uint(f);
  u += 0x7fffu + ((u >> 16) & 1u);
  return (u16)(u >> 16);
}
__device__ __forceinline__ float bf2f(u16 s) {
  return __uint_as_float(((unsigned)s) << 16);
}
__device__ __forceinline__ void async_load16(const void* g, void* l) {
  __builtin_amdgcn_global_load_lds((const __attribute__((address_space(1))) void*)g,
                                   (__attribute__((address_space(3))) void*)l, 16, 0, 0);
}

// ---------------- merged prep: castx | weight transpose+cast | gidx/bias ----------------
__global__ __launch_bounds__(256) void prep_all(const float* __restrict__ x,
                                                const float* __restrict__ Wq, const float* __restrict__ Wk,
                                                const float* __restrict__ Wv, const float* __restrict__ Wo,
                                                const int* __restrict__ gm,
                                                const float* __restrict__ bq, const float* __restrict__ bk,
                                                const float* __restrict__ bv,
                                                u16* __restrict__ xb, u16* __restrict__ wqkvT,
                                                u16* __restrict__ woT,
                                                int* __restrict__ gidx, float* __restrict__ biasqkv) {
  __shared__ float tile[32][33];
  const int bid = blockIdx.x;
  const int tid = threadIdx.x;
  if (bid < 3072) {                                  // ---- cast x, one float4/thread ----
    int i = bid * 256 + tid;
    float4 v = ((const float4*)x)[i];
    u16x4 o = { f2bf(v.x), f2bf(v.y), f2bf(v.z), f2bf(v.w) };
    ((u16x4*)xb)[i] = o;
  } else if (bid < 5376) {                           // ---- W(K,N) -> WT(N,K) bf16 ----
    int r = bid - 3072;
    int z = r / 576; r %= 576;
    int kx = r % 24, ny = r / 24;
    const float* W = (z == 0) ? Wq : (z == 1) ? Wk : (z == 2) ? Wv : Wo;
    u16* dst = (z < 3) ? (wqkvT + (size_t)z * DD * DD) : woT;
    int k0 = kx * 32, n0 = ny * 32;
    int tx = tid & 31, ty = tid >> 5;                // 32 x 8
#pragma unroll
    for (int j = 0; j < 4; ++j)
      tile[ty + j * 8][tx] = W[(size_t)(k0 + ty + j * 8) * DD + n0 + tx];
    __syncthreads();
#pragma unroll
    for (int j = 0; j < 4; ++j)
      dst[(size_t)(n0 + ty + j * 8) * DD + k0 + tx] = f2bf(tile[tx][ty + j * 8]);
  } else {                                           // ---- gidx + fused qkv bias ----
    for (int n = tid; n < NQKV; n += 256)
      biasqkv[n] = (n < 768) ? bq[n] : (n < 1536) ? bk[n - 768] : bv[n - 1536];
    if (tid < 64) {                                  // wave 0 only
      int lane = tid;
      if (lane < 32) gidx[lane] = 0;
      int base = 0;
      for (int c0 = 0; c0 < TT; c0 += 64) {
        int mval = gm[c0 + lane];
        unsigned long long bal = __ballot(mval != 0);
        int pre = __popcll(bal & ((1ull << lane) - 1ull));
        if (mval && (base + pre) < 32) gidx[base + pre] = c0 + lane;
        base += __popcll(bal);
        if (base >= 32) break;
      }
    }
  }
}

// ---------------- bf16 MFMA GEMM (qkv): C = A * BT^T + bias, 128x128 tile, bf16 out ----------------
__global__ __launch_bounds__(256) void gemm_qkv(const u16* __restrict__ A, const u16* __restrict__ BT,
                                                const float* __restrict__ bias, u16* __restrict__ C,
                                                int Ndim, int Kd) {
  __shared__ __attribute__((aligned(16))) u16 As[128 * 64];
  __shared__ __attribute__((aligned(16))) u16 Bs[128 * 64];
  const int tid = threadIdx.x;
  const int wave = tid >> 6, lane = tid & 63;
  const int m0 = blockIdx.x * 128, n0 = blockIdx.y * 128;
  const int wm = (wave & 1) << 6, wn = (wave >> 1) << 6;
  const int lr = lane & 15, lk = lane >> 4;
  const int srow_b = lane >> 3;
  const int scol = (lane & 7) * 8;

  f32x4 acc[4][4] = {};

  const int kIters = Kd >> 6;
  for (int kt = 0; kt < kIters; ++kt) {
#pragma unroll
    for (int cc = 0; cc < 4; ++cc) {
      int c = wave * 4 + cc;
      int srow = c * 8 + srow_b;
      async_load16(A + (size_t)(m0 + srow) * Kd + (kt << 6) + scol, (void*)(As + c * 512));
      async_load16(BT + (size_t)(n0 + srow) * Kd + (kt << 6) + scol, (void*)(Bs + c * 512));
    }
    __syncthreads();
#pragma unroll
    for (int kc = 0; kc < 2; ++kc) {
      bf16x8 af[4], bfr[4];
#pragma unroll
      for (int i = 0; i < 4; ++i)
        af[i] = *(const bf16x8*)(As + (wm + i * 16 + lr) * 64 + kc * 32 + lk * 8);
#pragma unroll
      for (int j = 0; j < 4; ++j)
        bfr[j] = *(const bf16x8*)(Bs + (wn + j * 16 + lr) * 64 + kc * 32 + lk * 8);
#pragma unroll
      for (int i = 0; i < 4; ++i)
#pragma unroll
        for (int j = 0; j < 4; ++j)
          acc[i][j] = __builtin_amdgcn_mfma_f32_16x16x32_bf16(af[i], bfr[j], acc[i][j], 0, 0, 0);
    }
    __syncthreads();
  }

#pragma unroll
  for (int i = 0; i < 4; ++i) {
    const int row = m0 + wm + i * 16 + lk * 4;
#pragma unroll
    for (int j = 0; j < 4; ++j) {
      const int col = n0 + wn + j * 16 + lr;
      const float bs = bias[col];
#pragma unroll
      for (int r = 0; r < 4; ++r)
        C[(size_t)(row + r) * Ndim + col] = f2bf(acc[i][j][r] + bs);
    }
  }
}

// ---------------- attention: one block = (b, h, 64 t-rows); ctx + fattn slab ----------------
// R4 skeleton (parked zero stores + quad-local band) with the dword scatter replaced by
// masked f32x4 composition:
//  - 32-iter register scan of gidxs -> gm0/gm1 (globals in this thread's two zero-slots)
//    and bg0..2 (globals in this quad's <=3 band slots). Row-independent.
//  - zero parker skips band slots AND global slots;
//  - band writer composes band+global in-register (same-wave probs reads);
//  - post-barrier composer: only threads with gm!=0 write their global slots for all 64
//    rows (outside band), fully composed f32x4 NT. No dword RMW, no scatter tail.
// Every slab slot written exactly once. Barriers never follow parked stores except the
// single post-ctx sync (which must drain anyway before cross-wave probs reads).
__global__ __launch_bounds__(256) void attn_kernel(const u16* __restrict__ qb,
                                                   const int* __restrict__ gidx,
                                                   u16* __restrict__ ctxb,
                                                   float* __restrict__ fattn) {
  __shared__ __attribute__((aligned(16))) u16 Kl[96 * 72];
  __shared__ __attribute__((aligned(16))) u16 Kg[32 * 72];
  __shared__ __attribute__((aligned(16))) u16 Vl[96 * 72];
  __shared__ __attribute__((aligned(16))) u16 Vg[32 * 72];
  __shared__ __attribute__((aligned(16))) float probs[64 * 66];
  __shared__ int gidxs[32];

  const int tid = threadIdx.x;
  const int blk = blockIdx.x;
  const int chunk = blk & 31;
  const int h = (blk >> 5) % NH;
  const int b = blk / 384;
  const int t0 = chunk << 6;

  float* fbase = fattn + ((size_t)(b * NH + h) * TT + t0) * TT;
  const f32x4 z4 = {0.f, 0.f, 0.f, 0.f};

  // zero-slot emitter: slot q in [0,32768) = (row rl=q>>9, f32x4-col j=q&511).
  // Skips band slots [bl4,bh4] of the row AND slots containing global columns (gmsk).
#define EMIT_ZERO(qslot, gmsk)                                               \
  {                                                                          \
    int q_ = (qslot);                                                        \
    int rl_ = q_ >> 9, j_ = q_ & 511;                                        \
    int tr_ = t0 + rl_;                                                      \
    int bl4_ = (tr_ >= 16) ? ((tr_ - 16) >> 2) : 0;                          \
    int th_ = tr_ + 16; if (th_ > TT - 1) th_ = TT - 1;                      \
    int bh4_ = th_ >> 2;                                                     \
    if ((j_ < bl4_ || j_ > bh4_) && (gmsk) == 0u)                            \
      __builtin_nontemporal_store(z4, (f32x4*)(fbase + (size_t)rl_ * TT + (j_ << 2))); \
  }

  // ---- phase 1: stage bf16 K/V + gidx + q->regs (q drained by the staging barrier) ----
  const int tl = tid >> 2, sub = tid & 3;
  const int t = t0 + tl;
  const u16* qp = qb + (size_t)(b * TT + t) * NQKV + h * HDIM;
  u16x8 qpk[8];                       // q packed bf16: 32 VGPRs
#pragma unroll
  for (int i = 0; i < 8; ++i) qpk[i] = *(const u16x8*)(qp + i * 8);

  {
    const int r = tid >> 3;
    const int c8 = (tid & 7) << 3;
#pragma unroll
    for (int it = 0; it < 3; ++it) {
      int rr = it * 32 + r;
      int tt = t0 - 16 + rr;
      tt = tt < 0 ? 0 : (tt > TT - 1 ? TT - 1 : tt);
      const u16* src = qb + (size_t)(b * TT + tt) * NQKV + h * HDIM + c8;
      *(u16x8*)(Kl + rr * 72 + c8) = *(const u16x8*)(src + 768);
      *(u16x8*)(Vl + rr * 72 + c8) = *(const u16x8*)(src + 1536);
    }
    {
      int tt = gidx[r];
      const u16* src = qb + (size_t)(b * TT + tt) * NQKV + h * HDIM + c8;
      *(u16x8*)(Kg + r * 72 + c8) = *(const u16x8*)(src + 768);
      *(u16x8*)(Vg + r * 72 + c8) = *(const u16x8*)(src + 1536);
    }
    if (tid < 32) gidxs[tid] = gidx[tid];
  }
  __syncthreads();

  // ---- phase 1b: per-thread global-column masks (register scan; all LDS reads done
  //      BEFORE any store is parked, so no later barrier concern) ----
  const int bl4 = (t >= 16) ? ((t - 16) >> 2) : 0;
  const int bh4 = (t + 16 > TT - 1 ? TT - 1 : t + 16) >> 2;
  unsigned gm0 = 0, gm1 = 0, bg0 = 0, bg1 = 0, bg2 = 0;
#pragma unroll 1
  for (int g = 0; g < 32; ++g) {
    int col = gidxs[g];
    int j = col >> 2, e = col & 3;
    unsigned tag = (0x80u | (unsigned)g) << (e << 3);
    if (j == tid)           gm0 |= tag;
    if (j == tid + 256)     gm1 |= tag;
    if (j == bl4 + sub)     bg0 |= tag;
    if (j == bl4 + sub + 4) bg1 |= tag;
    if (j == bl4 + sub + 8) bg2 |= tag;
  }

  // ---- phase 1c: park early zero-stores in the VMEM queue (issue-and-forget) ----
#pragma unroll 2
  for (int it = 0; it < 56; ++it) EMIT_ZERO(it * 256 + tid, (it & 1) ? gm1 : gm0);

  // ---- phase 2: scores + softmax. quad (4 threads) per t-row, scores strided by 4 ----
  float sc[17];
  float mmax = -__builtin_inff();
#pragma unroll
  for (int i = 0; i < 17; ++i) {
    const int s = sub + (i << 2);
    const u16* kp;
    bool valid;
    if (s < 33) { kp = Kl + (tl + s) * 72; int j = t - 16 + s; valid = (j >= 0) && (j < TT); }
    else if (s < 65) { kp = Kg + (s - 33) * 72; valid = true; }
    else { kp = Kg; valid = false; }
    float d = 0.f;
#pragma unroll
    for (int i2 = 0; i2 < 8; ++i2) {
      u16x8 kv = *(const u16x8*)(kp + i2 * 8);
      u16x8 qq = qpk[i2];
#pragma unroll
      for (int e = 0; e < 8; ++e) d += bf2f(qq[e]) * bf2f(kv[e]);
    }
    sc[i] = valid ? d * 0.125f : -__builtin_inff();
    mmax = fmaxf(mmax, sc[i]);
  }
  mmax = fmaxf(mmax, __shfl_xor(mmax, 1));
  mmax = fmaxf(mmax, __shfl_xor(mmax, 2));
  float sum = 0.f;
#pragma unroll
  for (int i = 0; i < 17; ++i) { sc[i] = __expf(sc[i] - mmax); sum += sc[i]; }
  sum += __shfl_xor(sum, 1);
  sum += __shfl_xor(sum, 2);
  const float inv = 1.0f / sum;
#pragma unroll
  for (int i = 0; i < 17; ++i) {
    const int s = sub + (i << 2);
    sc[i] *= inv;
    if (s < 65) probs[tl * 66 + s] = sc[i];
  }
  // No barrier: probs row tl is written and read by this quad's wave (DS ops are
  // program-ordered per wave). Cross-wave reads happen only after the final sync.

  // ---- phase 2b: band vectors of OWN row, globals composed in-register ----
  {
    const unsigned bgm[3] = {bg0, bg1, bg2};
#pragma unroll
    for (int r2 = 0; r2 < 3; ++r2) {
      int j = bl4 + sub + (r2 << 2);
      if (j <= bh4) {
        f32x4 v;
        unsigned bm = bgm[r2];
#pragma unroll
        for (int e = 0; e < 4; ++e) {
          int c = (j << 2) + e;
          int k = c - t + 16;
          float val = ((unsigned)k < 33u) ? probs[tl * 66 + k] : 0.f;
          unsigned byt = (bm >> (e << 3)) & 0xffu;
          if (byt & 0x80u) val = probs[tl * 66 + 33 + (byt & 31u)];
          v[e] = val;
        }
        __builtin_nontemporal_store(v, (f32x4*)(fbase + (size_t)tl * TT + (j << 2)));
      }
    }
  }

  // ---- phase 3: ctx (LDS/VALU only; parked stores keep draining) ----
  float cacc[16];
#pragma unroll
  for (int i = 0; i < 16; ++i) cacc[i] = 0.f;
#pragma unroll 1
  for (int k = 0; k < 65; ++k) {
    const float pv = probs[tl * 66 + k];
    const u16* vp = (k < 33) ? (Vl + (tl + k) * 72) : (Vg + (k - 33) * 72);
    const u16* vq = vp + (sub << 4);
    u16x8 v0 = *(const u16x8*)(vq);
    u16x8 v1 = *(const u16x8*)(vq + 8);
#pragma unroll
    for (int e = 0; e < 8; ++e) { cacc[e] += pv * bf2f(v0[e]); cacc[8 + e] += pv * bf2f(v1[e]); }
  }
  {
    u16x8 cb0, cb1;
#pragma unroll
    for (int e = 0; e < 8; ++e) { cb0[e] = f2bf(cacc[e]); cb1[e] = f2bf(cacc[8 + e]); }
    u16* dst = ctxb + (size_t)(b * TT + t) * DD + h * HDIM + (sub << 4);
    *(u16x8*)dst = cb0;
    *(u16x8*)(dst + 8) = cb1;
  }

  // ---- phase 3b: remaining zero-stores ----
#pragma unroll 2
  for (int it = 56; it < 128; ++it) EMIT_ZERO(it * 256 + tid, (it & 1) ? gm1 : gm0);

  __syncthreads();                    // all probs rows visible; parked stores drained

  // ---- phase 4: composer — global slots OUTSIDE band, all 64 rows, composed f32x4 ----
#pragma unroll
  for (int half = 0; half < 2; ++half) {
    const unsigned gmsk = half ? gm1 : gm0;
    if (gmsk) {
      const int j = tid + (half << 8);
#pragma unroll 1
      for (int rl = 0; rl < 64; ++rl) {
        int tr = t0 + rl;
        int rb = (tr >= 16) ? ((tr - 16) >> 2) : 0;
        int rh = (tr + 16 > TT - 1 ? TT - 1 : tr + 16) >> 2;
        if (j < rb || j > rh) {
          f32x4 v = {0.f, 0.f, 0.f, 0.f};
#pragma unroll
          for (int e = 0; e < 4; ++e) {
            unsigned byt = (gmsk >> (e << 3)) & 0xffu;
            if (byt & 0x80u) v[e] = probs[rl * 66 + 33 + (byt & 31u)];
          }
          __builtin_nontemporal_store(v, (f32x4*)(fbase + (size_t)rl * TT + (j << 2)));
        }
      }
    }
  }
#undef EMIT_ZERO
}

// ---------------- out-projection GEMM: out = ctx @ WoT^T + bo : BM=64, BN=128 tile ----------------
__global__ __launch_bounds__(256) void gemm_out(const u16* __restrict__ ctxb, const u16* __restrict__ woT,
                                                const float* __restrict__ bo, float* __restrict__ out) {
  __shared__ __attribute__((aligned(16))) u16 sA[64 * 64];
  __shared__ __attribute__((aligned(16))) u16 sB[128 * 64];
  const int tid = threadIdx.x;
  const int bid = blockIdx.x;
  const int wave = tid >> 6, lane = tid & 63;
  const int m0 = (bid & 63) * 64, n0 = (bid >> 6) * 128;
  const int wn = wave << 5;
  const int lr = lane & 15, lk = lane >> 4;
  const int srow_b = lane >> 3;
  const int scol = (lane & 7) * 8;

  f32x4 acc[4][2] = {};
  for (int kt = 0; kt < DD / 64; ++kt) {
#pragma unroll
    for (int cc = 0; cc < 2; ++cc) {
      int c = wave * 2 + cc;
      int srow = c * 8 + srow_b;
      async_load16(ctxb + (size_t)(m0 + srow) * DD + (kt << 6) + scol, (void*)(sA + c * 512));
    }
#pragma unroll
    for (int cc = 0; cc < 4; ++cc) {
      int c = wave * 4 + cc;
      int srow = c * 8 + srow_b;
      async_load16(woT + (size_t)(n0 + srow) * DD + (kt << 6) + scol, (void*)(sB + c * 512));
    }
    __syncthreads();
#pragma unroll
    for (int kc = 0; kc < 2; ++kc) {
      bf16x8 af[4], bfr[2];
#pragma unroll
      for (int i = 0; i < 4; ++i)
        af[i] = *(const bf16x8*)(sA + (i * 16 + lr) * 64 + kc * 32 + lk * 8);
#pragma unroll
      for (int j = 0; j < 2; ++j)
        bfr[j] = *(const bf16x8*)(sB + (wn + j * 16 + lr) * 64 + kc * 32 + lk * 8);
#pragma unroll
      for (int i = 0; i < 4; ++i)
#pragma unroll
        for (int j = 0; j < 2; ++j)
          acc[i][j] = __builtin_amdgcn_mfma_f32_16x16x32_bf16(af[i], bfr[j], acc[i][j], 0, 0, 0);
    }
    __syncthreads();
  }
#pragma unroll
  for (int i = 0; i < 4; ++i) {
    const int row = m0 + i * 16 + lk * 4;
#pragma unroll
    for (int j = 0; j < 2; ++j) {
      const int col = n0 + wn + j * 16 + lr;
      const float bs = bo[col];
#pragma unroll
      for (int r = 0; r < 4; ++r)
        out[(size_t)(row + r) * DD + col] = acc[i][j][r] + bs;
    }
  }
}

extern "C" void kernel_launch(void* const* d_in, const int* in_sizes, int n_in,
                              void* d_out, int out_size, void* d_ws, size_t ws_size,
                              hipStream_t stream) {
  const float* x  = (const float*)d_in[0];
  const int* gm   = (const int*)d_in[1];
  const float* Wq = (const float*)d_in[2];
  const float* bq = (const float*)d_in[3];
  const float* Wk = (const float*)d_in[4];
  const float* bk = (const float*)d_in[5];
  const float* Wv = (const float*)d_in[6];
  const float* bv = (const float*)d_in[7];
  const float* Wo = (const float*)d_in[8];
  const float* bo = (const float*)d_in[9];

  float* out = (float*)d_out;
  float* fattn = out + (size_t)BB * TT * DD;

  char* p = (char*)d_ws;
  u16* xb      = (u16*)p;  p += (size_t)MM * DD * 2;        // 6291456
  u16* wqkvT   = (u16*)p;  p += (size_t)NQKV * DD * 2;      // 3538944
  u16* woT     = (u16*)p;  p += (size_t)DD * DD * 2;        // 1179648
  float* biasq = (float*)p; p += (size_t)NQKV * 4;          // 9216
  int* gidx    = (int*)p;  p += 128;
  u16* qkvb    = (u16*)p;  p += (size_t)MM * NQKV * 2;      // 18874368 (bf16 qkv)
  u16* ctxb    = (u16*)p;  p += (size_t)MM * DD * 2;        // 6291456

  prep_all<<<5377, 256, 0, stream>>>(x, Wq, Wk, Wv, Wo, gm, bq, bk, bv,
                                     xb, wqkvT, woT, gidx, biasq);
  gemm_qkv<<<dim3(MM / 128, NQKV / 128), 256, 0, stream>>>(xb, wqkvT, biasq, qkvb, NQKV, DD);
  attn_kernel<<<BB * NH * (TT / 64), 256, 0, stream>>>(qkvb, gidx, ctxb, fattn);
  gemm_out<<<384, 256, 0, stream>>>(ctxb, woT, bo, out);
}

// Round 7
// 523.954 us; speedup vs baseline: 1.0704x; 1.0704x over previous
//
#include <hip/hip_runtime.h>

typedef unsigned short u16;
typedef __attribute__((ext_vector_type(4))) u16 u16x4;
typedef __attribute__((ext_vector_type(8))) u16 u16x8;
typedef __attribute__((ext_vector_type(8))) short bf16x8;
typedef __attribute__((ext_vector_type(4))) float f32x4;

// Problem constants
#define BB 2
#define TT 2048
#define DD 768
#define NH 12
#define HDIM 64
#define NQKV 2304   // 3*DD
#define MM 4096     // BB*TT

__device__ __forceinline__ u16 f2bf(float f) {
  unsigned u = __float_as_uint(f);
  u += 0x7fffu + ((u >> 16) & 1u);
  return (u16)(u >> 16);
}
__device__ __forceinline__ float bf2f(u16 s) {
  return __uint_as_float(((unsigned)s) << 16);
}
__device__ __forceinline__ void async_load16(const void* g, void* l) {
  __builtin_amdgcn_global_load_lds((const __attribute__((address_space(1))) void*)g,
                                   (__attribute__((address_space(3))) void*)l, 16, 0, 0);
}

// ---------------- merged prep: castx | weight transpose+cast | gidx/bias ----------------
__global__ __launch_bounds__(256) void prep_all(const float* __restrict__ x,
                                                const float* __restrict__ Wq, const float* __restrict__ Wk,
                                                const float* __restrict__ Wv, const float* __restrict__ Wo,
                                                const int* __restrict__ gm,
                                                const float* __restrict__ bq, const float* __restrict__ bk,
                                                const float* __restrict__ bv,
                                                u16* __restrict__ xb, u16* __restrict__ wqkvT,
                                                u16* __restrict__ woT,
                                                int* __restrict__ gidx, float* __restrict__ biasqkv) {
  __shared__ float tile[32][33];
  const int bid = blockIdx.x;
  const int tid = threadIdx.x;
  if (bid < 3072) {                                  // ---- cast x, one float4/thread ----
    int i = bid * 256 + tid;
    float4 v = ((const float4*)x)[i];
    u16x4 o = { f2bf(v.x), f2bf(v.y), f2bf(v.z), f2bf(v.w) };
    ((u16x4*)xb)[i] = o;
  } else if (bid < 5376) {                           // ---- W(K,N) -> WT(N,K) bf16 ----
    int r = bid - 3072;
    int z = r / 576; r %= 576;
    int kx = r % 24, ny = r / 24;
    const float* W = (z == 0) ? Wq : (z == 1) ? Wk : (z == 2) ? Wv : Wo;
    u16* dst = (z < 3) ? (wqkvT + (size_t)z * DD * DD) : woT;
    int k0 = kx * 32, n0 = ny * 32;
    int tx = tid & 31, ty = tid >> 5;                // 32 x 8
#pragma unroll
    for (int j = 0; j < 4; ++j)
      tile[ty + j * 8][tx] = W[(size_t)(k0 + ty + j * 8) * DD + n0 + tx];
    __syncthreads();
#pragma unroll
    for (int j = 0; j < 4; ++j)
      dst[(size_t)(n0 + ty + j * 8) * DD + k0 + tx] = f2bf(tile[tx][ty + j * 8]);
  } else {                                           // ---- gidx + fused qkv bias ----
    for (int n = tid; n < NQKV; n += 256)
      biasqkv[n] = (n < 768) ? bq[n] : (n < 1536) ? bk[n - 768] : bv[n - 1536];
    if (tid < 64) {                                  // wave 0 only
      int lane = tid;
      if (lane < 32) gidx[lane] = 0;
      int base = 0;
      for (int c0 = 0; c0 < TT; c0 += 64) {
        int mval = gm[c0 + lane];
        unsigned long long bal = __ballot(mval != 0);
        int pre = __popcll(bal & ((1ull << lane) - 1ull));
        if (mval && (base + pre) < 32) gidx[base + pre] = c0 + lane;
        base += __popcll(bal);
        if (base >= 32) break;
      }
    }
  }
}

// ---------------- bf16 MFMA GEMM (qkv): C = A * BT^T + bias, 128x128 tile, bf16 out ----------------
__global__ __launch_bounds__(256) void gemm_qkv(const u16* __restrict__ A, const u16* __restrict__ BT,
                                                const float* __restrict__ bias, u16* __restrict__ C,
                                                int Ndim, int Kd) {
  __shared__ __attribute__((aligned(16))) u16 As[128 * 64];
  __shared__ __attribute__((aligned(16))) u16 Bs[128 * 64];
  const int tid = threadIdx.x;
  const int wave = tid >> 6, lane = tid & 63;
  const int m0 = blockIdx.x * 128, n0 = blockIdx.y * 128;
  const int wm = (wave & 1) << 6, wn = (wave >> 1) << 6;
  const int lr = lane & 15, lk = lane >> 4;
  const int srow_b = lane >> 3;
  const int scol = (lane & 7) * 8;

  f32x4 acc[4][4] = {};

  const int kIters = Kd >> 6;
  for (int kt = 0; kt < kIters; ++kt) {
#pragma unroll
    for (int cc = 0; cc < 4; ++cc) {
      int c = wave * 4 + cc;
      int srow = c * 8 + srow_b;
      async_load16(A + (size_t)(m0 + srow) * Kd + (kt << 6) + scol, (void*)(As + c * 512));
      async_load16(BT + (size_t)(n0 + srow) * Kd + (kt << 6) + scol, (void*)(Bs + c * 512));
    }
    __syncthreads();
#pragma unroll
    for (int kc = 0; kc < 2; ++kc) {
      bf16x8 af[4], bfr[4];
#pragma unroll
      for (int i = 0; i < 4; ++i)
        af[i] = *(const bf16x8*)(As + (wm + i * 16 + lr) * 64 + kc * 32 + lk * 8);
#pragma unroll
      for (int j = 0; j < 4; ++j)
        bfr[j] = *(const bf16x8*)(Bs + (wn + j * 16 + lr) * 64 + kc * 32 + lk * 8);
#pragma unroll
      for (int i = 0; i < 4; ++i)
#pragma unroll
        for (int j = 0; j < 4; ++j)
          acc[i][j] = __builtin_amdgcn_mfma_f32_16x16x32_bf16(af[i], bfr[j], acc[i][j], 0, 0, 0);
    }
    __syncthreads();
  }

#pragma unroll
  for (int i = 0; i < 4; ++i) {
    const int row = m0 + wm + i * 16 + lk * 4;
#pragma unroll
    for (int j = 0; j < 4; ++j) {
      const int col = n0 + wn + j * 16 + lr;
      const float bs = bias[col];
#pragma unroll
      for (int r = 0; r < 4; ++r)
        C[(size_t)(row + r) * Ndim + col] = f2bf(acc[i][j][r] + bs);
    }
  }
}

// ---------------- attention: one block = (b, h, 64 t-rows); ctx + fattn slab ----------------
// Store/compute overlap via the VMEM queue (~63 outstanding ops/wave):
//   stage+qload -> barrier -> park 56 zero-stores/thread in the queue ->
//   scores+softmax+band+ctx (vmcnt-free: LDS/VALU only, stores drain underneath) ->
//   remaining 72 zero-stores -> barrier (drains vmcnt 0) -> global-col scatter.
// No mid-kernel barrier: probs rows are produced and consumed within one QUAD of one
// wave (same-wave DS ops are program-ordered); only the scatter reads cross-wave and
// it sits after the final barrier (verified write-all-then-overwrite pattern).
__global__ __launch_bounds__(256) void attn_kernel(const u16* __restrict__ qb,
                                                   const int* __restrict__ gidx,
                                                   u16* __restrict__ ctxb,
                                                   float* __restrict__ fattn) {
  __shared__ __attribute__((aligned(16))) u16 Kl[96 * 72];
  __shared__ __attribute__((aligned(16))) u16 Kg[32 * 72];
  __shared__ __attribute__((aligned(16))) u16 Vl[96 * 72];
  __shared__ __attribute__((aligned(16))) u16 Vg[32 * 72];
  __shared__ __attribute__((aligned(16))) float probs[64 * 66];
  __shared__ int gidxs[32];

  const int tid = threadIdx.x;
  const int blk = blockIdx.x;
  const int chunk = blk & 31;
  const int h = (blk >> 5) % NH;
  const int b = blk / 384;
  const int t0 = chunk << 6;

  float* fbase = fattn + ((size_t)(b * NH + h) * TT + t0) * TT;
  const f32x4 z4 = {0.f, 0.f, 0.f, 0.f};

  // zero-slot emitter: slot q in [0, 32768) = (row rl = q>>9, f32x4-col j = q&511).
  // Skips band slots [bl4, bh4] (written by the band writer).
#define EMIT_ZERO(qslot)                                                     \
  {                                                                          \
    int q_ = (qslot);                                                        \
    int rl_ = q_ >> 9, j_ = q_ & 511;                                        \
    int tr_ = t0 + rl_;                                                      \
    int bl4_ = (tr_ >= 16) ? ((tr_ - 16) >> 2) : 0;                          \
    int th_ = tr_ + 16; if (th_ > TT - 1) th_ = TT - 1;                      \
    int bh4_ = th_ >> 2;                                                     \
    if (j_ < bl4_ || j_ > bh4_)                                              \
      __builtin_nontemporal_store(z4, (f32x4*)(fbase + (size_t)rl_ * TT + (j_ << 2))); \
  }

  // ---- phase 1: stage bf16 K/V + gidx + q->regs (q drained by the staging barrier) ----
  const int tl = tid >> 2, sub = tid & 3;
  const int t = t0 + tl;
  const u16* qp = qb + (size_t)(b * TT + t) * NQKV + h * HDIM;
  u16x8 qpk[8];                       // q packed bf16: 32 VGPRs
#pragma unroll
  for (int i = 0; i < 8; ++i) qpk[i] = *(const u16x8*)(qp + i * 8);

  {
    const int r = tid >> 3;
    const int c8 = (tid & 7) << 3;
#pragma unroll
    for (int it = 0; it < 3; ++it) {
      int rr = it * 32 + r;
      int tt = t0 - 16 + rr;
      tt = tt < 0 ? 0 : (tt > TT - 1 ? TT - 1 : tt);
      const u16* src = qb + (size_t)(b * TT + tt) * NQKV + h * HDIM + c8;
      *(u16x8*)(Kl + rr * 72 + c8) = *(const u16x8*)(src + 768);
      *(u16x8*)(Vl + rr * 72 + c8) = *(const u16x8*)(src + 1536);
    }
    {
      int tt = gidx[r];
      const u16* src = qb + (size_t)(b * TT + tt) * NQKV + h * HDIM + c8;
      *(u16x8*)(Kg + r * 72 + c8) = *(const u16x8*)(src + 768);
      *(u16x8*)(Vg + r * 72 + c8) = *(const u16x8*)(src + 1536);
    }
    if (tid < 32) gidxs[tid] = gidx[tid];
  }
  __syncthreads();

  // ---- phase 1b: park early zero-stores in the VMEM queue (issue-and-forget) ----
#pragma unroll 2
  for (int it = 0; it < 56; ++it) EMIT_ZERO(it * 256 + tid);

  // ---- phase 2: scores + softmax. quad (4 threads) per t-row, scores strided by 4 ----
  float sc[17];
  float mmax = -__builtin_inff();
#pragma unroll
  for (int i = 0; i < 17; ++i) {
    const int s = sub + (i << 2);
    const u16* kp;
    bool valid;
    if (s < 33) { kp = Kl + (tl + s) * 72; int j = t - 16 + s; valid = (j >= 0) && (j < TT); }
    else if (s < 65) { kp = Kg + (s - 33) * 72; valid = true; }
    else { kp = Kg; valid = false; }
    float d = 0.f;
#pragma unroll
    for (int i2 = 0; i2 < 8; ++i2) {
      u16x8 kv = *(const u16x8*)(kp + i2 * 8);
      u16x8 qq = qpk[i2];
#pragma unroll
      for (int e = 0; e < 8; ++e) d += bf2f(qq[e]) * bf2f(kv[e]);
    }
    sc[i] = valid ? d * 0.125f : -__builtin_inff();
    mmax = fmaxf(mmax, sc[i]);
  }
  mmax = fmaxf(mmax, __shfl_xor(mmax, 1));
  mmax = fmaxf(mmax, __shfl_xor(mmax, 2));
  float sum = 0.f;
#pragma unroll
  for (int i = 0; i < 17; ++i) { sc[i] = __expf(sc[i] - mmax); sum += sc[i]; }
  sum += __shfl_xor(sum, 1);
  sum += __shfl_xor(sum, 2);
  const float inv = 1.0f / sum;
#pragma unroll
  for (int i = 0; i < 17; ++i) {
    const int s = sub + (i << 2);
    sc[i] *= inv;
    if (s < 65) probs[tl * 66 + s] = sc[i];
  }
  // NO barrier: probs row tl is written and read by the same quad (same wave,
  // DS ops program-ordered). Cross-wave consumption happens only after the
  // final __syncthreads below.

  // ---- phase 2b: band vectors of OWN row (quad-local; zeros elsewhere already queued) ----
  {
    int bl4 = (t >= 16) ? ((t - 16) >> 2) : 0;
    int th = t + 16; if (th > TT - 1) th = TT - 1;
    int bh4 = th >> 2;
#pragma unroll
    for (int r2 = 0; r2 < 3; ++r2) {
      int j = bl4 + sub + (r2 << 2);
      if (j <= bh4) {
        f32x4 v;
#pragma unroll
        for (int e = 0; e < 4; ++e) {
          int c = (j << 2) + e;
          int k = c - t + 16;
          v[e] = ((unsigned)k < 33u) ? probs[tl * 66 + k] : 0.f;
        }
        __builtin_nontemporal_store(v, (f32x4*)(fbase + (size_t)tl * TT + (j << 2)));
      }
    }
  }

  // ---- phase 3: ctx (LDS/VALU only; stores keep draining) ----
  float cacc[16];
#pragma unroll
  for (int i = 0; i < 16; ++i) cacc[i] = 0.f;
#pragma unroll 1
  for (int k = 0; k < 65; ++k) {
    const float pv = probs[tl * 66 + k];
    const u16* vp = (k < 33) ? (Vl + (tl + k) * 72) : (Vg + (k - 33) * 72);
    const u16* vq = vp + (sub << 4);
    u16x8 v0 = *(const u16x8*)(vq);
    u16x8 v1 = *(const u16x8*)(vq + 8);
#pragma unroll
    for (int e = 0; e < 8; ++e) { cacc[e] += pv * bf2f(v0[e]); cacc[8 + e] += pv * bf2f(v1[e]); }
  }
  {
    u16x8 cb0, cb1;
#pragma unroll
    for (int e = 0; e < 8; ++e) { cb0[e] = f2bf(cacc[e]); cb1[e] = f2bf(cacc[8 + e]); }
    u16* dst = ctxb + (size_t)(b * TT + t) * DD + h * HDIM + (sub << 4);
    *(u16x8*)dst = cb0;
    *(u16x8*)(dst + 8) = cb1;
  }

  // ---- phase 3b: remaining zero-stores ----
#pragma unroll 2
  for (int it = 56; it < 128; ++it) EMIT_ZERO(it * 256 + tid);

  __syncthreads();                    // drains vmcnt(0): all zero+band stores complete
  // ---- phase 4: global-column overwrite (general scattered gidx) ----
#pragma unroll
  for (int rep = 0; rep < 8; ++rep) {
    int w = rep * 256 + tid;
    int rl = w >> 5, g = w & 31;
    fbase[(size_t)rl * TT + gidxs[g]] = probs[rl * 66 + 33 + g];
  }
#undef EMIT_ZERO
}

// ---------------- out-projection GEMM: out = ctx @ WoT^T + bo : BM=64, BN=128 tile ----------------
__global__ __launch_bounds__(256) void gemm_out(const u16* __restrict__ ctxb, const u16* __restrict__ woT,
                                                const float* __restrict__ bo, float* __restrict__ out) {
  __shared__ __attribute__((aligned(16))) u16 sA[64 * 64];
  __shared__ __attribute__((aligned(16))) u16 sB[128 * 64];
  const int tid = threadIdx.x;
  const int bid = blockIdx.x;
  const int wave = tid >> 6, lane = tid & 63;
  const int m0 = (bid & 63) * 64, n0 = (bid >> 6) * 128;
  const int wn = wave << 5;
  const int lr = lane & 15, lk = lane >> 4;
  const int srow_b = lane >> 3;
  const int scol = (lane & 7) * 8;

  f32x4 acc[4][2] = {};
  for (int kt = 0; kt < DD / 64; ++kt) {
#pragma unroll
    for (int cc = 0; cc < 2; ++cc) {
      int c = wave * 2 + cc;
      int srow = c * 8 + srow_b;
      async_load16(ctxb + (size_t)(m0 + srow) * DD + (kt << 6) + scol, (void*)(sA + c * 512));
    }
#pragma unroll
    for (int cc = 0; cc < 4; ++cc) {
      int c = wave * 4 + cc;
      int srow = c * 8 + srow_b;
      async_load16(woT + (size_t)(n0 + srow) * DD + (kt << 6) + scol, (void*)(sB + c * 512));
    }
    __syncthreads();
#pragma unroll
    for (int kc = 0; kc < 2; ++kc) {
      bf16x8 af[4], bfr[2];
#pragma unroll
      for (int i = 0; i < 4; ++i)
        af[i] = *(const bf16x8*)(sA + (i * 16 + lr) * 64 + kc * 32 + lk * 8);
#pragma unroll
      for (int j = 0; j < 2; ++j)
        bfr[j] = *(const bf16x8*)(sB + (wn + j * 16 + lr) * 64 + kc * 32 + lk * 8);
#pragma unroll
      for (int i = 0; i < 4; ++i)
#pragma unroll
        for (int j = 0; j < 2; ++j)
          acc[i][j] = __builtin_amdgcn_mfma_f32_16x16x32_bf16(af[i], bfr[j], acc[i][j], 0, 0, 0);
    }
    __syncthreads();
  }
#pragma unroll
  for (int i = 0; i < 4; ++i) {
    const int row = m0 + i * 16 + lk * 4;
#pragma unroll
    for (int j = 0; j < 2; ++j) {
      const int col = n0 + wn + j * 16 + lr;
      const float bs = bo[col];
#pragma unroll
      for (int r = 0; r < 4; ++r)
        out[(size_t)(row + r) * DD + col] = acc[i][j][r] + bs;
    }
  }
}

extern "C" void kernel_launch(void* const* d_in, const int* in_sizes, int n_in,
                              void* d_out, int out_size, void* d_ws, size_t ws_size,
                              hipStream_t stream) {
  const float* x  = (const float*)d_in[0];
  const int* gm   = (const int*)d_in[1];
  const float* Wq = (const float*)d_in[2];
  const float* bq = (const float*)d_in[3];
  const float* Wk = (const float*)d_in[4];
  const float* bk = (const float*)d_in[5];
  const float* Wv = (const float*)d_in[6];
  const float* bv = (const float*)d_in[7];
  const float* Wo = (const float*)d_in[8];
  const float* bo = (const float*)d_in[9];

  float* out = (float*)d_out;
  float* fattn = out + (size_t)BB * TT * DD;

  char* p = (char*)d_ws;
  u16* xb      = (u16*)p;  p += (size_t)MM * DD * 2;        // 6291456
  u16* wqkvT   = (u16*)p;  p += (size_t)NQKV * DD * 2;      // 3538944
  u16* woT     = (u16*)p;  p += (size_t)DD * DD * 2;        // 1179648
  float* biasq = (float*)p; p += (size_t)NQKV * 4;          // 9216
  int* gidx    = (int*)p;  p += 128;
  u16* qkvb    = (u16*)p;  p += (size_t)MM * NQKV * 2;      // 18874368 (bf16 qkv)
  u16* ctxb    = (u16*)p;  p += (size_t)MM * DD * 2;        // 6291456

  prep_all<<<5377, 256, 0, stream>>>(x, Wq, Wk, Wv, Wo, gm, bq, bk, bv,
                                     xb, wqkvT, woT, gidx, biasq);
  gemm_qkv<<<dim3(MM / 128, NQKV / 128), 256, 0, stream>>>(xb, wqkvT, biasq, qkvb, NQKV, DD);
  attn_kernel<<<BB * NH * (TT / 64), 256, 0, stream>>>(qkvb, gidx, ctxb, fattn);
  gemm_out<<<384, 256, 0, stream>>>(ctxb, woT, bo, out);
}